// Round 1
// baseline (867.101 us; speedup 1.0000x reference)
//
#include <hip/hip_runtime.h>

typedef short bhalf8 __attribute__((ext_vector_type(8)));
typedef float floatx4 __attribute__((ext_vector_type(4)));

__device__ __forceinline__ unsigned short f2bf(float f){
  union { float f; unsigned int u; } v; v.f = f;
  unsigned int u = v.u;
  u += 0x7fffu + ((u >> 16) & 1u);
  return (unsigned short)(u >> 16);
}

// ---------------------------------------------------------------------------
// Generic MFMA GEMM: C[M,N] = A[M,K] * B[K,N], B supplied TRANSPOSED (BT[N,K], bf16).
// Tile 128x128, BK=32, 4 waves (2x2), each wave 64x64 via 4x4 mfma_f32_16x16x32_bf16.
// EPI 0: store fp32 C[m*ldc+n]
// EPI 1: store fp32 C[m*ldc+n] + bias[n]
// EPI 2: store bf16 TRANSPOSED Cb[n*ldc+m]
// ---------------------------------------------------------------------------
template<bool AF32, int EPI>
__global__ __launch_bounds__(256) void gemm_k(
    const void* __restrict__ Aptr, const unsigned short* __restrict__ BT,
    const float* __restrict__ bias, float* __restrict__ Cf,
    unsigned short* __restrict__ Cb, int K, int ldc)
{
  __shared__ __align__(16) unsigned short As[128*40]; // pad stride 40 elems (80B)
  __shared__ __align__(16) unsigned short Bs[128*40];
  const int tid = threadIdx.x;
  const int m0 = blockIdx.x * 128;
  const int n0 = blockIdx.y * 128;
  const int wid = tid >> 6, lane = tid & 63;
  const int wr = (wid >> 1) * 64, wc = (wid & 1) * 64;
  const int r16 = lane & 15, quad = lane >> 4;

  floatx4 acc[4][4];
  #pragma unroll
  for (int i=0;i<4;i++)
    #pragma unroll
    for (int j=0;j<4;j++) acc[i][j] = {0.f,0.f,0.f,0.f};

  for (int k0 = 0; k0 < K; k0 += 32) {
    if (AF32) {
      const float* Af = (const float*)Aptr;
      #pragma unroll
      for (int i = 0; i < 4; ++i) {
        int s = tid + i*256;                 // 1024 float4 slots
        int row = s >> 3, c4 = (s & 7) << 2; // 8 float4 per 32-elem row
        float4 v = *(const float4*)(Af + (size_t)(m0+row)*K + k0 + c4);
        uint2 p;
        p.x = (unsigned)f2bf(v.x) | ((unsigned)f2bf(v.y) << 16);
        p.y = (unsigned)f2bf(v.z) | ((unsigned)f2bf(v.w) << 16);
        *(uint2*)&As[row*40 + c4] = p;
      }
    } else {
      const unsigned short* Ab = (const unsigned short*)Aptr;
      #pragma unroll
      for (int i = 0; i < 2; ++i) {
        int s = tid + i*256;                 // 512 16B chunks
        int row = s >> 2, c8 = (s & 3) << 3;
        *(uint4*)&As[row*40 + c8] = *(const uint4*)(Ab + (size_t)(m0+row)*K + k0 + c8);
      }
    }
    #pragma unroll
    for (int i = 0; i < 2; ++i) {
      int s = tid + i*256;
      int row = s >> 2, c8 = (s & 3) << 3;
      *(uint4*)&Bs[row*40 + c8] = *(const uint4*)(BT + (size_t)(n0+row)*K + k0 + c8);
    }
    __syncthreads();
    bhalf8 aF[4], bF[4];
    #pragma unroll
    for (int mi=0;mi<4;++mi) aF[mi] = *(const bhalf8*)&As[(wr + mi*16 + r16)*40 + quad*8];
    #pragma unroll
    for (int ni=0;ni<4;++ni) bF[ni] = *(const bhalf8*)&Bs[(wc + ni*16 + r16)*40 + quad*8];
    #pragma unroll
    for (int mi=0;mi<4;++mi)
      #pragma unroll
      for (int ni=0;ni<4;++ni)
        acc[mi][ni] = __builtin_amdgcn_mfma_f32_16x16x32_bf16(aF[mi], bF[ni], acc[mi][ni], 0, 0, 0);
    __syncthreads();
  }
  #pragma unroll
  for (int mi=0;mi<4;++mi)
    #pragma unroll
    for (int ni=0;ni<4;++ni)
      #pragma unroll
      for (int r=0;r<4;++r){
        int m = m0 + wr + mi*16 + quad*4 + r;
        int n = n0 + wc + ni*16 + r16;
        float val = acc[mi][ni][r];
        if (EPI == 0) Cf[(size_t)m*ldc + n] = val;
        else if (EPI == 1) Cf[(size_t)m*ldc + n] = val + bias[n];
        else Cb[(size_t)n*ldc + m] = f2bf(val);
      }
}

// Tiled transpose fp32[R,C] -> bf16[C,R]
__global__ __launch_bounds__(256) void transpose_cvt(const float* __restrict__ src,
                                                     unsigned short* __restrict__ dst,
                                                     int R, int C)
{
  __shared__ float tile[32][33];
  int c0 = blockIdx.x*32, r0 = blockIdx.y*32;
  int tx = threadIdx.x, ty = threadIdx.y; // 32 x 8
  #pragma unroll
  for (int i=0;i<32;i+=8)
    tile[ty+i][tx] = src[(size_t)(r0+ty+i)*C + c0+tx];
  __syncthreads();
  #pragma unroll
  for (int i=0;i<32;i+=8)
    dst[(size_t)(c0+ty+i)*R + r0+tx] = f2bf(tile[tx][ty+i]);
}

// straight fp32 -> bf16 copy (4 elems/thread)
__global__ __launch_bounds__(256) void cvt_f32_bf16(const float* __restrict__ src,
                                                    unsigned short* __restrict__ dst)
{
  int idx = (blockIdx.x*256 + threadIdx.x) * 4;
  float4 v = *(const float4*)(src + idx);
  uint2 p;
  p.x = (unsigned)f2bf(v.x) | ((unsigned)f2bf(v.y) << 16);
  p.y = (unsigned)f2bf(v.z) | ((unsigned)f2bf(v.w) << 16);
  *(uint2*)(dst + idx) = p;
}

// b_comb[d] = b_proj[d] + sum_e b_out[e]*W_proj[e][d];  a_vec[d] = exp(log_a[d])
__global__ __launch_bounds__(256) void prep_small(const float* __restrict__ b_out,
                                                  const float* __restrict__ W_proj,
                                                  const float* __restrict__ b_proj,
                                                  const float* __restrict__ log_a,
                                                  float* __restrict__ b_comb,
                                                  float* __restrict__ a_vec)
{
  int d = blockIdx.x*256 + threadIdx.x;
  float acc = b_proj[d];
  for (int e = 0; e < 1024; ++e)
    acc += b_out[e] * W_proj[(size_t)e*1024 + d];
  b_comb[d] = acc;
  a_vec[d] = __expf(log_a[d]);
}

// ---- 3-phase chunked scan over T. pre[M,2048]: cols 0..1023 = ih preact, 1024..2047 = gate preact.
// chunk length 128, 64 chunks per sequence, B=4 sequences.
__device__ __forceinline__ void alphabeta(float zi, float zg, float a, float& al, float& be)
{
  float g = 1.f / (1.f + __expf(-zg));
  al = (1.f - g) * a;
  be = g * zi;
}

__global__ __launch_bounds__(256) void scan_phase1(const float* __restrict__ pre,
    const float* __restrict__ b_ih, const float* __restrict__ b_gate,
    const float* __restrict__ a_vec, float* __restrict__ Asum, float* __restrict__ Ssum)
{
  int tid = threadIdx.x;
  int hg = blockIdx.x & 3;
  int c  = (blockIdx.x >> 2) & 63;
  int b  = blockIdx.x >> 8;
  int n = hg*256 + tid;
  float bi = b_ih[n], bg = b_gate[n], a = a_vec[n];
  float A = 1.f, S = 0.f;
  size_t base = ((size_t)(b*8192 + c*128)) * 2048 + n;
  for (int t = 0; t < 128; ++t) {
    float zi = pre[base] + bi;
    float zg = pre[base + 1024] + bg;
    float al, be; alphabeta(zi, zg, a, al, be);
    A *= al;
    S = al*S + be;
    base += 2048;
  }
  size_t o = ((size_t)(b*64 + c))*1024 + n;
  Asum[o] = A; Ssum[o] = S;
}

__global__ __launch_bounds__(256) void scan_phase2(const float* __restrict__ Asum,
    const float* __restrict__ Ssum, float* __restrict__ carry)
{
  int idx = blockIdx.x*256 + threadIdx.x; // 4096 = B*H
  int b = idx >> 10, n = idx & 1023;
  float cur = 0.f;
  for (int c = 0; c < 64; ++c) {
    size_t o = ((size_t)(b*64 + c))*1024 + n;
    carry[o] = cur;
    cur = Asum[o]*cur + Ssum[o];
  }
}

__global__ __launch_bounds__(256) void scan_phase3(const float* __restrict__ pre,
    const float* __restrict__ b_ih, const float* __restrict__ b_gate,
    const float* __restrict__ a_vec, const float* __restrict__ carry,
    float* __restrict__ hbuf)
{
  int tid = threadIdx.x;
  int hg = blockIdx.x & 3;
  int c  = (blockIdx.x >> 2) & 63;
  int b  = blockIdx.x >> 8;
  int n = hg*256 + tid;
  float bi = b_ih[n], bg = b_gate[n], a = a_vec[n];
  float h = carry[((size_t)(b*64 + c))*1024 + n];
  size_t base = ((size_t)(b*8192 + c*128)) * 2048 + n;
  size_t ho   = ((size_t)(b*8192 + c*128)) * 1024 + n;
  for (int t = 0; t < 128; ++t) {
    float zi = pre[base] + bi;
    float zg = pre[base + 1024] + bg;
    float al, be; alphabeta(zi, zg, a, al, be);
    h = al*h + be;
    hbuf[ho] = h;
    base += 2048; ho += 1024;
  }
}

// LayerNorm over H=1024, one block (256 thr) per row, output bf16
__global__ __launch_bounds__(256) void ln_kernel(const float* __restrict__ hbuf,
    const float* __restrict__ ln_g, const float* __restrict__ ln_b,
    unsigned short* __restrict__ hn)
{
  int row = blockIdx.x, tid = threadIdx.x;
  const float4 v = *(const float4*)(hbuf + (size_t)row*1024 + tid*4);
  float s  = v.x + v.y + v.z + v.w;
  float s2 = v.x*v.x + v.y*v.y + v.z*v.z + v.w*v.w;
  #pragma unroll
  for (int off = 32; off > 0; off >>= 1) {
    s  += __shfl_down(s,  off);
    s2 += __shfl_down(s2, off);
  }
  __shared__ float ps[4], ps2[4];
  __shared__ float mu_s, rstd_s;
  int wid = tid >> 6, lane = tid & 63;
  if (lane == 0) { ps[wid] = s; ps2[wid] = s2; }
  __syncthreads();
  if (tid == 0) {
    float S = ps[0]+ps[1]+ps[2]+ps[3];
    float S2 = ps2[0]+ps2[1]+ps2[2]+ps2[3];
    float mu = S * (1.f/1024.f);
    float var = S2 * (1.f/1024.f) - mu*mu;
    mu_s = mu; rstd_s = rsqrtf(var + 1e-5f);
  }
  __syncthreads();
  float mu = mu_s, rstd = rstd_s;
  const float4 g = *(const float4*)(ln_g + tid*4);
  const float4 bb = *(const float4*)(ln_b + tid*4);
  float o0 = (v.x - mu)*rstd*g.x + bb.x;
  float o1 = (v.y - mu)*rstd*g.y + bb.y;
  float o2 = (v.z - mu)*rstd*g.z + bb.z;
  float o3 = (v.w - mu)*rstd*g.w + bb.w;
  uint2 p;
  p.x = (unsigned)f2bf(o0) | ((unsigned)f2bf(o1) << 16);
  p.y = (unsigned)f2bf(o2) | ((unsigned)f2bf(o3) << 16);
  *(uint2*)(hn + (size_t)row*1024 + tid*4) = p;
}

extern "C" void kernel_launch(void* const* d_in, const int* in_sizes, int n_in,
                              void* d_out, int out_size, void* d_ws, size_t ws_size,
                              hipStream_t stream)
{
  const float* x      = (const float*)d_in[0];
  const float* W_ih   = (const float*)d_in[1];
  const float* b_ih   = (const float*)d_in[2];
  const float* W_gate = (const float*)d_in[3];
  const float* b_gate = (const float*)d_in[4];
  const float* log_a  = (const float*)d_in[5];
  const float* ln_g   = (const float*)d_in[6];
  const float* ln_b   = (const float*)d_in[7];
  const float* W_out  = (const float*)d_in[8];
  const float* b_out  = (const float*)d_in[9];
  const float* W_proj = (const float*)d_in[10];
  const float* b_proj = (const float*)d_in[11];
  float* out = (float*)d_out;

  char* ws = (char*)d_ws;
  size_t off = 0;
  auto alloc = [&](size_t bytes)->char* {
    char* p = ws + off; off += (bytes + 255) & ~(size_t)255; return p;
  };
  float* pre            = (float*)alloc((size_t)32768*2048*4);   // 256 MB
  float* hbuf           = (float*)alloc((size_t)32768*1024*4);   // 128 MB
  unsigned short* hn    = (unsigned short*)alloc((size_t)32768*1024*2); // 64 MB
  unsigned short* WcatT = (unsigned short*)alloc((size_t)2048*1024*2);  // [n=2048][k=1024]
  unsigned short* WprojT= (unsigned short*)alloc((size_t)1024*1024*2);
  unsigned short* Woutb = (unsigned short*)alloc((size_t)1024*1024*2);
  unsigned short* WcombT= (unsigned short*)alloc((size_t)1024*1024*2);
  float* Asum           = (float*)alloc((size_t)4*64*1024*4);
  float* Ssum           = (float*)alloc((size_t)4*64*1024*4);
  float* carry          = (float*)alloc((size_t)4*64*1024*4);
  float* b_comb         = (float*)alloc(1024*4);
  float* a_vec          = (float*)alloc(1024*4);

  dim3 t32x8(32, 8);
  // weight prep
  transpose_cvt<<<dim3(32,32), t32x8, 0, stream>>>(W_ih,   WcatT,              1024, 1024);
  transpose_cvt<<<dim3(32,32), t32x8, 0, stream>>>(W_gate, WcatT + 1024*1024,  1024, 1024);
  transpose_cvt<<<dim3(32,32), t32x8, 0, stream>>>(W_proj, WprojT,             1024, 1024);
  cvt_f32_bf16<<<1024, 256, 0, stream>>>(W_out, Woutb);
  prep_small<<<4, 256, 0, stream>>>(b_out, W_proj, b_proj, log_a, b_comb, a_vec);
  // WcombT[d][h] = (W_out @ W_proj)^T : GEMM M=h,N=d,K=e with transposed bf16 store
  gemm_k<false,2><<<dim3(8,8), 256, 0, stream>>>(Woutb, WprojT, nullptr, nullptr, WcombT, 1024, 1024);
  // pre[M,2048] = x @ [W_ih | W_gate]
  gemm_k<true,0><<<dim3(256,16), 256, 0, stream>>>(x, WcatT, nullptr, pre, nullptr, 1024, 2048);
  // chunked scan
  scan_phase1<<<1024, 256, 0, stream>>>(pre, b_ih, b_gate, a_vec, Asum, Ssum);
  scan_phase2<<<16, 256, 0, stream>>>(Asum, Ssum, carry);
  scan_phase3<<<1024, 256, 0, stream>>>(pre, b_ih, b_gate, a_vec, carry, hbuf);
  // layernorm -> bf16
  ln_kernel<<<32768, 256, 0, stream>>>(hbuf, ln_g, ln_b, hn);
  // out = hn @ Wcomb + b_comb
  gemm_k<false,1><<<dim3(256,8), 256, 0, stream>>>(hn, WcombT, b_comb, out, nullptr, 1024, 1024);
}

// Round 2
// 772.048 us; speedup vs baseline: 1.1231x; 1.1231x over previous
//
#include <hip/hip_runtime.h>

typedef short bhalf8 __attribute__((ext_vector_type(8)));
typedef float floatx4 __attribute__((ext_vector_type(4)));

__device__ __forceinline__ unsigned short f2bf(float f){
  union { float f; unsigned int u; } v; v.f = f;
  unsigned int u = v.u;
  u += 0x7fffu + ((u >> 16) & 1u);
  return (unsigned short)(u >> 16);
}

__device__ __forceinline__ void async16(const unsigned short* g, unsigned short* l){
  __builtin_amdgcn_global_load_lds(
      (const __attribute__((address_space(1))) void*)g,
      (__attribute__((address_space(3))) void*)l,
      16, 0, 0);
}

// ---------------------------------------------------------------------------
// MFMA GEMM: C[M,N] = A[M,K] * B[K,N]; A bf16 [M,K], B given transposed bf16 BT[N,K].
// Tile 128x128, BK=32, 4 waves (2x2), each wave 64x64 via 4x4 mfma_f32_16x16x32_bf16.
// Staging: global_load_lds width=16, XOR-swizzled LDS layout (slot = row*4 + (c ^ ((row>>1)&3)))
//   -> conflict-free-ish ds_read_b128 fragment reads (2-way only), no padding.
// grid: (N/128, M/128) -- n-tile fastest for A-panel L2 reuse.
// EPI 0: store fp32 C[m*ldc+n]
// EPI 1: store fp32 C[m*ldc+n] + bias[n]
// EPI 2: store bf16 TRANSPOSED Cb[n*ldc+m]
// ---------------------------------------------------------------------------
template<int EPI>
__global__ __launch_bounds__(256) void gemm_k(
    const unsigned short* __restrict__ Ab, const unsigned short* __restrict__ BT,
    const float* __restrict__ bias, float* __restrict__ Cf,
    unsigned short* __restrict__ Cb, int K, int ldc)
{
  __shared__ __align__(16) unsigned short As[128*32];
  __shared__ __align__(16) unsigned short Bs[128*32];
  const int tid = threadIdx.x;
  const int n0 = blockIdx.x * 128;
  const int m0 = blockIdx.y * 128;
  const int wid = tid >> 6, lane = tid & 63;
  const int wr = (wid >> 1) * 64, wc = (wid & 1) * 64;
  const int r16 = lane & 15, quad = lane >> 4;
  const int slotbase = tid & ~63;   // wave-uniform

  floatx4 acc[4][4];
  #pragma unroll
  for (int i=0;i<4;i++)
    #pragma unroll
    for (int j=0;j<4;j++) acc[i][j] = {0.f,0.f,0.f,0.f};

  // precompute swizzled fragment LDS offsets (ushort index)
  int aoff[4], boff[4];
  #pragma unroll
  for (int mi=0;mi<4;++mi){
    int row = wr + mi*16 + r16;
    aoff[mi] = (row*4 + (quad ^ ((row>>1)&3))) * 8;
  }
  #pragma unroll
  for (int ni=0;ni<4;++ni){
    int row = wc + ni*16 + r16;
    boff[ni] = (row*4 + (quad ^ ((row>>1)&3))) * 8;
  }

  for (int k0 = 0; k0 < K; k0 += 32) {
    #pragma unroll
    for (int i = 0; i < 2; ++i) {
      int p = tid + i*256;               // linear LDS slot (16B chunks)
      int row = p >> 2;
      int c = (p & 3) ^ ((row >> 1) & 3); // inverse swizzle: which global chunk lands here
      async16(Ab + (size_t)(m0+row)*K + k0 + c*8, &As[(slotbase + i*256)*8]);
    }
    #pragma unroll
    for (int i = 0; i < 2; ++i) {
      int p = tid + i*256;
      int row = p >> 2;
      int c = (p & 3) ^ ((row >> 1) & 3);
      async16(BT + (size_t)(n0+row)*K + k0 + c*8, &Bs[(slotbase + i*256)*8]);
    }
    __syncthreads();   // compiler emits s_waitcnt vmcnt(0) before s_barrier
    bhalf8 aF[4], bF[4];
    #pragma unroll
    for (int mi=0;mi<4;++mi) aF[mi] = *(const bhalf8*)&As[aoff[mi]];
    #pragma unroll
    for (int ni=0;ni<4;++ni) bF[ni] = *(const bhalf8*)&Bs[boff[ni]];
    #pragma unroll
    for (int mi=0;mi<4;++mi)
      #pragma unroll
      for (int ni=0;ni<4;++ni)
        acc[mi][ni] = __builtin_amdgcn_mfma_f32_16x16x32_bf16(aF[mi], bF[ni], acc[mi][ni], 0, 0, 0);
    __syncthreads();
  }
  #pragma unroll
  for (int mi=0;mi<4;++mi)
    #pragma unroll
    for (int ni=0;ni<4;++ni)
      #pragma unroll
      for (int r=0;r<4;++r){
        int m = m0 + wr + mi*16 + quad*4 + r;
        int n = n0 + wc + ni*16 + r16;
        float val = acc[mi][ni][r];
        if (EPI == 0) Cf[(size_t)m*ldc + n] = val;
        else if (EPI == 1) Cf[(size_t)m*ldc + n] = val + bias[n];
        else Cb[(size_t)n*ldc + m] = f2bf(val);
      }
}

// Tiled transpose fp32[R,C] -> bf16[C,R]
__global__ __launch_bounds__(256) void transpose_cvt(const float* __restrict__ src,
                                                     unsigned short* __restrict__ dst,
                                                     int R, int C)
{
  __shared__ float tile[32][33];
  int c0 = blockIdx.x*32, r0 = blockIdx.y*32;
  int tx = threadIdx.x, ty = threadIdx.y; // 32 x 8
  #pragma unroll
  for (int i=0;i<32;i+=8)
    tile[ty+i][tx] = src[(size_t)(r0+ty+i)*C + c0+tx];
  __syncthreads();
  #pragma unroll
  for (int i=0;i<32;i+=8)
    dst[(size_t)(c0+ty+i)*R + r0+tx] = f2bf(tile[tx][ty+i]);
}

// straight fp32 -> bf16 copy (4 elems/thread)
__global__ __launch_bounds__(256) void cvt_f32_bf16(const float* __restrict__ src,
                                                    unsigned short* __restrict__ dst)
{
  int idx = (blockIdx.x*256 + threadIdx.x) * 4;
  float4 v = *(const float4*)(src + idx);
  uint2 p;
  p.x = (unsigned)f2bf(v.x) | ((unsigned)f2bf(v.y) << 16);
  p.y = (unsigned)f2bf(v.z) | ((unsigned)f2bf(v.w) << 16);
  *(uint2*)(dst + idx) = p;
}

// b_comb[d] = b_proj[d] + sum_e b_out[e]*W_proj[e][d];  a_vec[d] = exp(log_a[d])
__global__ __launch_bounds__(256) void prep_small(const float* __restrict__ b_out,
                                                  const float* __restrict__ W_proj,
                                                  const float* __restrict__ b_proj,
                                                  const float* __restrict__ log_a,
                                                  float* __restrict__ b_comb,
                                                  float* __restrict__ a_vec)
{
  int d = blockIdx.x*256 + threadIdx.x;
  float acc = b_proj[d];
  for (int e = 0; e < 1024; ++e)
    acc += b_out[e] * W_proj[(size_t)e*1024 + d];
  b_comb[d] = acc;
  a_vec[d] = __expf(log_a[d]);
}

// ---- 3-phase chunked scan over T. pre[M,2048]: cols 0..1023 = ih preact, 1024..2047 = gate preact.
__device__ __forceinline__ void alphabeta(float zi, float zg, float a, float& al, float& be)
{
  float g = 1.f / (1.f + __expf(-zg));
  al = (1.f - g) * a;
  be = g * zi;
}

__global__ __launch_bounds__(256) void scan_phase1(const float* __restrict__ pre,
    const float* __restrict__ b_ih, const float* __restrict__ b_gate,
    const float* __restrict__ a_vec, float* __restrict__ Asum, float* __restrict__ Ssum)
{
  int tid = threadIdx.x;
  int hg = blockIdx.x & 3;
  int c  = (blockIdx.x >> 2) & 63;
  int b  = blockIdx.x >> 8;
  int n = hg*256 + tid;
  float bi = b_ih[n], bg = b_gate[n], a = a_vec[n];
  float A = 1.f, S = 0.f;
  size_t base = ((size_t)(b*8192 + c*128)) * 2048 + n;
  for (int t = 0; t < 128; ++t) {
    float zi = pre[base] + bi;
    float zg = pre[base + 1024] + bg;
    float al, be; alphabeta(zi, zg, a, al, be);
    A *= al;
    S = al*S + be;
    base += 2048;
  }
  size_t o = ((size_t)(b*64 + c))*1024 + n;
  Asum[o] = A; Ssum[o] = S;
}

__global__ __launch_bounds__(256) void scan_phase2(const float* __restrict__ Asum,
    const float* __restrict__ Ssum, float* __restrict__ carry)
{
  int idx = blockIdx.x*256 + threadIdx.x; // 4096 = B*H
  int b = idx >> 10, n = idx & 1023;
  float cur = 0.f;
  for (int c = 0; c < 64; ++c) {
    size_t o = ((size_t)(b*64 + c))*1024 + n;
    carry[o] = cur;
    cur = Asum[o]*cur + Ssum[o];
  }
}

__global__ __launch_bounds__(256) void scan_phase3(const float* __restrict__ pre,
    const float* __restrict__ b_ih, const float* __restrict__ b_gate,
    const float* __restrict__ a_vec, const float* __restrict__ carry,
    float* __restrict__ hbuf)
{
  int tid = threadIdx.x;
  int hg = blockIdx.x & 3;
  int c  = (blockIdx.x >> 2) & 63;
  int b  = blockIdx.x >> 8;
  int n = hg*256 + tid;
  float bi = b_ih[n], bg = b_gate[n], a = a_vec[n];
  float h = carry[((size_t)(b*64 + c))*1024 + n];
  size_t base = ((size_t)(b*8192 + c*128)) * 2048 + n;
  size_t ho   = ((size_t)(b*8192 + c*128)) * 1024 + n;
  for (int t = 0; t < 128; ++t) {
    float zi = pre[base] + bi;
    float zg = pre[base + 1024] + bg;
    float al, be; alphabeta(zi, zg, a, al, be);
    h = al*h + be;
    hbuf[ho] = h;
    base += 2048; ho += 1024;
  }
}

// LayerNorm over H=1024, one block (256 thr) per row, output bf16
__global__ __launch_bounds__(256) void ln_kernel(const float* __restrict__ hbuf,
    const float* __restrict__ ln_g, const float* __restrict__ ln_b,
    unsigned short* __restrict__ hn)
{
  int row = blockIdx.x, tid = threadIdx.x;
  const float4 v = *(const float4*)(hbuf + (size_t)row*1024 + tid*4);
  float s  = v.x + v.y + v.z + v.w;
  float s2 = v.x*v.x + v.y*v.y + v.z*v.z + v.w*v.w;
  #pragma unroll
  for (int off = 32; off > 0; off >>= 1) {
    s  += __shfl_down(s,  off);
    s2 += __shfl_down(s2, off);
  }
  __shared__ float ps[4], ps2[4];
  __shared__ float mu_s, rstd_s;
  int wid = tid >> 6, lane = tid & 63;
  if (lane == 0) { ps[wid] = s; ps2[wid] = s2; }
  __syncthreads();
  if (tid == 0) {
    float S = ps[0]+ps[1]+ps[2]+ps[3];
    float S2 = ps2[0]+ps2[1]+ps2[2]+ps2[3];
    float mu = S * (1.f/1024.f);
    float var = S2 * (1.f/1024.f) - mu*mu;
    mu_s = mu; rstd_s = rsqrtf(var + 1e-5f);
  }
  __syncthreads();
  float mu = mu_s, rstd = rstd_s;
  const float4 g = *(const float4*)(ln_g + tid*4);
  const float4 bb = *(const float4*)(ln_b + tid*4);
  float o0 = (v.x - mu)*rstd*g.x + bb.x;
  float o1 = (v.y - mu)*rstd*g.y + bb.y;
  float o2 = (v.z - mu)*rstd*g.z + bb.z;
  float o3 = (v.w - mu)*rstd*g.w + bb.w;
  uint2 p;
  p.x = (unsigned)f2bf(o0) | ((unsigned)f2bf(o1) << 16);
  p.y = (unsigned)f2bf(o2) | ((unsigned)f2bf(o3) << 16);
  *(uint2*)(hn + (size_t)row*1024 + tid*4) = p;
}

extern "C" void kernel_launch(void* const* d_in, const int* in_sizes, int n_in,
                              void* d_out, int out_size, void* d_ws, size_t ws_size,
                              hipStream_t stream)
{
  const float* x      = (const float*)d_in[0];
  const float* W_ih   = (const float*)d_in[1];
  const float* b_ih   = (const float*)d_in[2];
  const float* W_gate = (const float*)d_in[3];
  const float* b_gate = (const float*)d_in[4];
  const float* log_a  = (const float*)d_in[5];
  const float* ln_g   = (const float*)d_in[6];
  const float* ln_b   = (const float*)d_in[7];
  const float* W_out  = (const float*)d_in[8];
  const float* b_out  = (const float*)d_in[9];
  const float* W_proj = (const float*)d_in[10];
  const float* b_proj = (const float*)d_in[11];
  float* out = (float*)d_out;

  char* ws = (char*)d_ws;
  size_t off = 0;
  auto alloc = [&](size_t bytes)->char* {
    char* p = ws + off; off += (bytes + 255) & ~(size_t)255; return p;
  };
  float* pre            = (float*)alloc((size_t)32768*2048*4);   // 256 MB
  float* hbuf           = (float*)alloc((size_t)32768*1024*4);   // 128 MB
  unsigned short* hn    = (unsigned short*)alloc((size_t)32768*1024*2); // 64 MB (aliased: xb first, hn later)
  unsigned short* xb    = hn;   // x in bf16; dead before hn is written
  unsigned short* WcatT = (unsigned short*)alloc((size_t)2048*1024*2);  // [n=2048][k=1024]
  unsigned short* WprojT= (unsigned short*)alloc((size_t)1024*1024*2);
  unsigned short* Woutb = (unsigned short*)alloc((size_t)1024*1024*2);
  unsigned short* WcombT= (unsigned short*)alloc((size_t)1024*1024*2);
  float* Asum           = (float*)alloc((size_t)4*64*1024*4);
  float* Ssum           = (float*)alloc((size_t)4*64*1024*4);
  float* carry          = (float*)alloc((size_t)4*64*1024*4);
  float* b_comb         = (float*)alloc(1024*4);
  float* a_vec          = (float*)alloc(1024*4);

  dim3 t32x8(32, 8);
  // weight prep
  transpose_cvt<<<dim3(32,32), t32x8, 0, stream>>>(W_ih,   WcatT,              1024, 1024);
  transpose_cvt<<<dim3(32,32), t32x8, 0, stream>>>(W_gate, WcatT + 1024*1024,  1024, 1024);
  transpose_cvt<<<dim3(32,32), t32x8, 0, stream>>>(W_proj, WprojT,             1024, 1024);
  cvt_f32_bf16<<<1024, 256, 0, stream>>>(W_out, Woutb);
  prep_small<<<4, 256, 0, stream>>>(b_out, W_proj, b_proj, log_a, b_comb, a_vec);
  // x -> bf16
  cvt_f32_bf16<<<32768, 256, 0, stream>>>(x, xb);
  // WcombT[d][h] = (W_out @ W_proj)^T : GEMM M=h,N=d,K=e with transposed bf16 store
  gemm_k<2><<<dim3(8,8), 256, 0, stream>>>(Woutb, WprojT, nullptr, nullptr, WcombT, 1024, 1024);
  // pre[M,2048] = x @ [W_ih | W_gate]   (grid: n-tiles fast)
  gemm_k<0><<<dim3(16,256), 256, 0, stream>>>(xb, WcatT, nullptr, pre, nullptr, 1024, 2048);
  // chunked scan
  scan_phase1<<<1024, 256, 0, stream>>>(pre, b_ih, b_gate, a_vec, Asum, Ssum);
  scan_phase2<<<16, 256, 0, stream>>>(Asum, Ssum, carry);
  scan_phase3<<<1024, 256, 0, stream>>>(pre, b_ih, b_gate, a_vec, carry, hbuf);
  // layernorm -> bf16
  ln_kernel<<<32768, 256, 0, stream>>>(hbuf, ln_g, ln_b, hn);
  // out = hn @ Wcomb + b_comb
  gemm_k<1><<<dim3(8,256), 256, 0, stream>>>(hn, WcombT, b_comb, out, nullptr, 1024, 1024);
}

// Round 3
// 735.683 us; speedup vs baseline: 1.1786x; 1.0494x over previous
//
#include <hip/hip_runtime.h>

typedef short bhalf8 __attribute__((ext_vector_type(8)));
typedef float floatx4 __attribute__((ext_vector_type(4)));
typedef unsigned short ushortx8 __attribute__((ext_vector_type(8)));

__device__ __forceinline__ unsigned short f2bf(float f){
  union { float f; unsigned int u; } v; v.f = f;
  unsigned int u = v.u;
  u += 0x7fffu + ((u >> 16) & 1u);
  return (unsigned short)(u >> 16);
}
__device__ __forceinline__ float bf2f(unsigned short u){
  union { unsigned int u; float f; } v; v.u = ((unsigned)u) << 16; return v.f;
}
__device__ __forceinline__ unsigned pack2(float a, float b){
  return (unsigned)f2bf(a) | ((unsigned)f2bf(b) << 16);
}

__device__ __forceinline__ void async16(const unsigned short* g, unsigned short* l){
  __builtin_amdgcn_global_load_lds(
      (const __attribute__((address_space(1))) void*)g,
      (__attribute__((address_space(3))) void*)l,
      16, 0, 0);
}

// ---------------------------------------------------------------------------
// MFMA GEMM: C[M,N] = A[M,K]*B[K,N]; A bf16 [M,K], B transposed bf16 BT[N,K].
// Tile 128x128, BK=64 (32 KB LDS), 4 waves 2x2, 4x4 mfma_f32_16x16x32_bf16 each.
// Staging: global_load_lds w=16, XOR swizzle slot=(row*8 + (c ^ (row&7))),
// staging pointers hoisted + incremented (no per-iter addr math).
// EPI 0: fp32 C;  1: fp32 C+bias;  2: bf16 transposed;  3: bf16 C+bias
// ---------------------------------------------------------------------------
template<int EPI>
__global__ __launch_bounds__(256) void gemm_k(
    const unsigned short* __restrict__ Ab, const unsigned short* __restrict__ BT,
    const float* __restrict__ bias, float* __restrict__ Cf,
    unsigned short* __restrict__ Cb, int K, int ldc)
{
  __shared__ __align__(16) unsigned short As[128*64];
  __shared__ __align__(16) unsigned short Bs[128*64];
  const int tid = threadIdx.x;
  const int n0 = blockIdx.x * 128;
  const int m0 = blockIdx.y * 128;
  const int wid = tid >> 6, lane = tid & 63;
  const int wr = (wid >> 1) * 64, wc = (wid & 1) * 64;
  const int r16 = lane & 15, quad = lane >> 4;
  const int ldsbase = (tid & ~63) * 8;   // wave-uniform ushort index

  // hoisted staging pointers: thread's 4 slots for A and B
  const unsigned short* pA[4];
  const unsigned short* pB[4];
  #pragma unroll
  for (int i = 0; i < 4; ++i) {
    int p = tid + i*256;
    int row = p >> 3;
    int cp = (p & 7) ^ (row & 7);     // global chunk that lands in this slot
    pA[i] = Ab + (size_t)(m0+row)*K + cp*8;
    pB[i] = BT + (size_t)(n0+row)*K + cp*8;
  }
  // fragment LDS offsets (ushort index), 2 k-steps
  int aoff[2][4], boff[2][4];
  #pragma unroll
  for (int ks = 0; ks < 2; ++ks){
    #pragma unroll
    for (int mi = 0; mi < 4; ++mi){
      int row = wr + mi*16 + r16;
      aoff[ks][mi] = (row*8 + ((ks*4+quad) ^ (row&7))) * 8;
    }
    #pragma unroll
    for (int ni = 0; ni < 4; ++ni){
      int row = wc + ni*16 + r16;
      boff[ks][ni] = (row*8 + ((ks*4+quad) ^ (row&7))) * 8;
    }
  }

  floatx4 acc[4][4];
  #pragma unroll
  for (int i=0;i<4;i++)
    #pragma unroll
    for (int j=0;j<4;j++) acc[i][j] = {0.f,0.f,0.f,0.f};

  for (int k0 = 0; k0 < K; k0 += 64) {
    #pragma unroll
    for (int i = 0; i < 4; ++i) async16(pA[i], &As[ldsbase + i*2048]);
    #pragma unroll
    for (int i = 0; i < 4; ++i) async16(pB[i], &Bs[ldsbase + i*2048]);
    __syncthreads();
    #pragma unroll
    for (int ks = 0; ks < 2; ++ks) {
      bhalf8 aF[4], bF[4];
      #pragma unroll
      for (int mi=0;mi<4;++mi) aF[mi] = *(const bhalf8*)&As[aoff[ks][mi]];
      #pragma unroll
      for (int ni=0;ni<4;++ni) bF[ni] = *(const bhalf8*)&Bs[boff[ks][ni]];
      #pragma unroll
      for (int mi=0;mi<4;++mi)
        #pragma unroll
        for (int ni=0;ni<4;++ni)
          acc[mi][ni] = __builtin_amdgcn_mfma_f32_16x16x32_bf16(aF[mi], bF[ni], acc[mi][ni], 0, 0, 0);
    }
    __syncthreads();
    #pragma unroll
    for (int i = 0; i < 4; ++i) { pA[i] += 64; pB[i] += 64; }
  }

  #pragma unroll
  for (int mi=0;mi<4;++mi)
    #pragma unroll
    for (int ni=0;ni<4;++ni)
      #pragma unroll
      for (int r=0;r<4;++r){
        int m = m0 + wr + mi*16 + quad*4 + r;
        int n = n0 + wc + ni*16 + r16;
        float val = acc[mi][ni][r];
        if (EPI == 0) Cf[(size_t)m*ldc + n] = val;
        else if (EPI == 1) Cf[(size_t)m*ldc + n] = val + bias[n];
        else if (EPI == 3) Cb[(size_t)m*ldc + n] = f2bf(val + bias[n]);
        else Cb[(size_t)n*ldc + m] = f2bf(val);
      }
}

// Tiled transpose fp32[R,C] -> bf16[C,R]
__global__ __launch_bounds__(256) void transpose_cvt(const float* __restrict__ src,
                                                     unsigned short* __restrict__ dst,
                                                     int R, int C)
{
  __shared__ float tile[32][33];
  int c0 = blockIdx.x*32, r0 = blockIdx.y*32;
  int tx = threadIdx.x, ty = threadIdx.y; // 32 x 8
  #pragma unroll
  for (int i=0;i<32;i+=8)
    tile[ty+i][tx] = src[(size_t)(r0+ty+i)*C + c0+tx];
  __syncthreads();
  #pragma unroll
  for (int i=0;i<32;i+=8)
    dst[(size_t)(c0+ty+i)*R + r0+tx] = f2bf(tile[tx][ty+i]);
}

// fp32 -> bf16 copy (4 elems/thread)
__global__ __launch_bounds__(256) void cvt_f32_bf16(const float* __restrict__ src,
                                                    unsigned short* __restrict__ dst)
{
  int idx = (blockIdx.x*256 + threadIdx.x) * 4;
  float4 v = *(const float4*)(src + idx);
  uint2 p;
  p.x = pack2(v.x, v.y);
  p.y = pack2(v.z, v.w);
  *(uint2*)(dst + idx) = p;
}

// b_comb = b_out@W_proj + b_proj; a_vec = exp(log_a); bcat = [b_ih | b_gate]
__global__ __launch_bounds__(256) void prep_small(const float* __restrict__ b_out,
                                                  const float* __restrict__ W_proj,
                                                  const float* __restrict__ b_proj,
                                                  const float* __restrict__ log_a,
                                                  const float* __restrict__ b_ih,
                                                  const float* __restrict__ b_gate,
                                                  float* __restrict__ b_comb,
                                                  float* __restrict__ a_vec,
                                                  float* __restrict__ bcat)
{
  int d = blockIdx.x*256 + threadIdx.x;  // 0..2047
  if (d < 1024) {
    float acc = b_proj[d];
    for (int e = 0; e < 1024; ++e)
      acc += b_out[e] * W_proj[(size_t)e*1024 + d];
    b_comb[d] = acc;
    a_vec[d] = __expf(log_a[d]);
    bcat[d] = b_ih[d];
  } else {
    bcat[d] = b_gate[d-1024];
  }
}

// ---------------------------------------------------------------------------
// Chunked scan, chunk length 8, 1024 chunks/seq. One WAVE owns all H=1024
// channels (16 ch/lane) of one (b,chunk) unit -> LN fuses with shfl_xor only.
// pre bf16 [M,2048]: cols 0..1023 ih preact (+bias), 1024..2047 gate preact.
// ---------------------------------------------------------------------------
__device__ __forceinline__ void ab_step(unsigned short iu, unsigned short gu,
                                        float a, float& al, float& be)
{
  float zi = bf2f(iu), zg = bf2f(gu);
  float g = 1.f / (1.f + __expf(-zg));
  al = (1.f - g) * a;
  be = g * zi;
}

__global__ __launch_bounds__(256, 4) void scan_phase1(const unsigned short* __restrict__ pre,
    const float* __restrict__ a_vec, float* __restrict__ Asum, float* __restrict__ Ssum)
{
  int wid = threadIdx.x >> 6, lane = threadIdx.x & 63;
  int u = blockIdx.x*4 + wid;      // unit = b*1024 + chunk
  int b = u >> 10, c = u & 1023;
  int ch0 = lane*16;
  float a[16], A[16], S[16];
  #pragma unroll
  for (int q=0;q<4;++q) *(float4*)&a[q*4] = *(const float4*)(a_vec + ch0 + q*4);
  #pragma unroll
  for (int j=0;j<16;++j){ A[j]=1.f; S[j]=0.f; }
  size_t base = ((size_t)(b*8192 + c*8))*2048 + ch0;
  for (int t=0;t<8;++t){
    ushortx8 i0 = *(const ushortx8*)(pre + base);
    ushortx8 i1 = *(const ushortx8*)(pre + base + 8);
    ushortx8 g0 = *(const ushortx8*)(pre + base + 1024);
    ushortx8 g1 = *(const ushortx8*)(pre + base + 1032);
    #pragma unroll
    for (int j=0;j<8;++j){
      float al, be;
      ab_step(i0[j], g0[j], a[j], al, be);
      A[j] *= al; S[j] = al*S[j] + be;
      ab_step(i1[j], g1[j], a[j+8], al, be);
      A[j+8] *= al; S[j+8] = al*S[j+8] + be;
    }
    base += 2048;
  }
  size_t o = (size_t)u*1024 + ch0;
  #pragma unroll
  for (int q=0;q<4;++q){
    *(float4*)(Asum + o + q*4) = *(const float4*)&A[q*4];
    *(float4*)(Ssum + o + q*4) = *(const float4*)&S[q*4];
  }
}

__global__ __launch_bounds__(256) void scan_phase2(const float* __restrict__ Asum,
    const float* __restrict__ Ssum, float* __restrict__ carry)
{
  int idx = blockIdx.x*256 + threadIdx.x; // 4096 = B*H
  int b = idx >> 10, n = idx & 1023;
  float cur = 0.f;
  size_t o = (size_t)b*1024*1024 + n;
  for (int c = 0; c < 1024; ++c) {
    carry[o] = cur;
    cur = Asum[o]*cur + Ssum[o];
    o += 1024;
  }
}

// phase3: recurrence + fused LayerNorm (wave-wide shfl_xor reduce) -> hn bf16
__global__ __launch_bounds__(256, 4) void scan_phase3(const unsigned short* __restrict__ pre,
    const float* __restrict__ a_vec, const float* __restrict__ carry,
    const float* __restrict__ ln_g, const float* __restrict__ ln_b,
    unsigned short* __restrict__ hn)
{
  int wid = threadIdx.x >> 6, lane = threadIdx.x & 63;
  int u = blockIdx.x*4 + wid;
  int b = u >> 10, c = u & 1023;
  int ch0 = lane*16;
  float a[16], h[16], g[16], lb[16];
  #pragma unroll
  for (int q=0;q<4;++q){
    *(float4*)&a[q*4]  = *(const float4*)(a_vec + ch0 + q*4);
    *(float4*)&h[q*4]  = *(const float4*)(carry + (size_t)u*1024 + ch0 + q*4);
    *(float4*)&g[q*4]  = *(const float4*)(ln_g + ch0 + q*4);
    *(float4*)&lb[q*4] = *(const float4*)(ln_b + ch0 + q*4);
  }
  size_t base  = ((size_t)(b*8192 + c*8))*2048 + ch0;
  size_t hbase = ((size_t)(b*8192 + c*8))*1024 + ch0;
  for (int t=0;t<8;++t){
    ushortx8 i0 = *(const ushortx8*)(pre + base);
    ushortx8 i1 = *(const ushortx8*)(pre + base + 8);
    ushortx8 g0 = *(const ushortx8*)(pre + base + 1024);
    ushortx8 g1 = *(const ushortx8*)(pre + base + 1032);
    float s = 0.f, s2 = 0.f;
    #pragma unroll
    for (int j=0;j<8;++j){
      float al, be;
      ab_step(i0[j], g0[j], a[j], al, be);
      h[j] = al*h[j] + be;
      s += h[j]; s2 += h[j]*h[j];
      ab_step(i1[j], g1[j], a[j+8], al, be);
      h[j+8] = al*h[j+8] + be;
      s += h[j+8]; s2 += h[j+8]*h[j+8];
    }
    #pragma unroll
    for (int off = 32; off > 0; off >>= 1) {
      s  += __shfl_xor(s,  off);
      s2 += __shfl_xor(s2, off);
    }
    float mu = s * (1.f/1024.f);
    float var = s2 * (1.f/1024.f) - mu*mu;
    float rstd = rsqrtf(var + 1e-5f);
    uint4 o0, o1;
    float v0, v1;
    v0 = (h[0]-mu)*rstd*g[0]+lb[0];  v1 = (h[1]-mu)*rstd*g[1]+lb[1];  o0.x = pack2(v0,v1);
    v0 = (h[2]-mu)*rstd*g[2]+lb[2];  v1 = (h[3]-mu)*rstd*g[3]+lb[3];  o0.y = pack2(v0,v1);
    v0 = (h[4]-mu)*rstd*g[4]+lb[4];  v1 = (h[5]-mu)*rstd*g[5]+lb[5];  o0.z = pack2(v0,v1);
    v0 = (h[6]-mu)*rstd*g[6]+lb[6];  v1 = (h[7]-mu)*rstd*g[7]+lb[7];  o0.w = pack2(v0,v1);
    v0 = (h[8]-mu)*rstd*g[8]+lb[8];  v1 = (h[9]-mu)*rstd*g[9]+lb[9];  o1.x = pack2(v0,v1);
    v0 = (h[10]-mu)*rstd*g[10]+lb[10]; v1 = (h[11]-mu)*rstd*g[11]+lb[11]; o1.y = pack2(v0,v1);
    v0 = (h[12]-mu)*rstd*g[12]+lb[12]; v1 = (h[13]-mu)*rstd*g[13]+lb[13]; o1.z = pack2(v0,v1);
    v0 = (h[14]-mu)*rstd*g[14]+lb[14]; v1 = (h[15]-mu)*rstd*g[15]+lb[15]; o1.w = pack2(v0,v1);
    *(uint4*)(hn + hbase)     = o0;
    *(uint4*)(hn + hbase + 8) = o1;
    base += 2048; hbase += 1024;
  }
}

extern "C" void kernel_launch(void* const* d_in, const int* in_sizes, int n_in,
                              void* d_out, int out_size, void* d_ws, size_t ws_size,
                              hipStream_t stream)
{
  const float* x      = (const float*)d_in[0];
  const float* W_ih   = (const float*)d_in[1];
  const float* b_ih   = (const float*)d_in[2];
  const float* W_gate = (const float*)d_in[3];
  const float* b_gate = (const float*)d_in[4];
  const float* log_a  = (const float*)d_in[5];
  const float* ln_g   = (const float*)d_in[6];
  const float* ln_b   = (const float*)d_in[7];
  const float* W_out  = (const float*)d_in[8];
  const float* b_out  = (const float*)d_in[9];
  const float* W_proj = (const float*)d_in[10];
  const float* b_proj = (const float*)d_in[11];
  float* out = (float*)d_out;

  char* ws = (char*)d_ws;
  size_t off = 0;
  auto alloc = [&](size_t bytes)->char* {
    char* p = ws + off; off += (bytes + 255) & ~(size_t)255; return p;
  };
  unsigned short* pre   = (unsigned short*)alloc((size_t)32768*2048*2); // 128 MB bf16
  unsigned short* hn    = (unsigned short*)alloc((size_t)32768*1024*2); // 64 MB (aliased w/ xb)
  unsigned short* xb    = hn;   // x bf16; dead before hn is written
  unsigned short* WcatT = (unsigned short*)alloc((size_t)2048*1024*2);
  unsigned short* WprojT= (unsigned short*)alloc((size_t)1024*1024*2);
  unsigned short* Woutb = (unsigned short*)alloc((size_t)1024*1024*2);
  unsigned short* WcombT= (unsigned short*)alloc((size_t)1024*1024*2);
  float* Asum           = (float*)alloc((size_t)4*1024*1024*4);  // 16 MB
  float* Ssum           = (float*)alloc((size_t)4*1024*1024*4);
  float* carry          = (float*)alloc((size_t)4*1024*1024*4);
  float* b_comb         = (float*)alloc(1024*4);
  float* a_vec          = (float*)alloc(1024*4);
  float* bcat           = (float*)alloc(2048*4);

  dim3 t32x8(32, 8);
  // weight prep
  transpose_cvt<<<dim3(32,32), t32x8, 0, stream>>>(W_ih,   WcatT,              1024, 1024);
  transpose_cvt<<<dim3(32,32), t32x8, 0, stream>>>(W_gate, WcatT + 1024*1024,  1024, 1024);
  transpose_cvt<<<dim3(32,32), t32x8, 0, stream>>>(W_proj, WprojT,             1024, 1024);
  cvt_f32_bf16<<<1024, 256, 0, stream>>>(W_out, Woutb);
  prep_small<<<8, 256, 0, stream>>>(b_out, W_proj, b_proj, log_a, b_ih, b_gate,
                                    b_comb, a_vec, bcat);
  // x -> bf16
  cvt_f32_bf16<<<32768, 256, 0, stream>>>(x, xb);
  // WcombT = (W_out @ W_proj)^T
  gemm_k<2><<<dim3(8,8), 256, 0, stream>>>(Woutb, WprojT, nullptr, nullptr, WcombT, 1024, 1024);
  // pre[M,2048] = bf16(x @ [W_ih|W_gate] + bcat)
  gemm_k<3><<<dim3(16,256), 256, 0, stream>>>(xb, WcatT, bcat, nullptr, pre, 1024, 2048);
  // chunked scan (chunk=8) + fused LN
  scan_phase1<<<1024, 256, 0, stream>>>(pre, a_vec, Asum, Ssum);
  scan_phase2<<<16, 256, 0, stream>>>(Asum, Ssum, carry);
  scan_phase3<<<1024, 256, 0, stream>>>(pre, a_vec, carry, ln_g, ln_b, hn);
  // out = hn @ Wcomb + b_comb
  gemm_k<1><<<dim3(8,256), 256, 0, stream>>>(hn, WcombT, b_comb, out, nullptr, 1024, 1024);
}